// Round 6
// baseline (589.616 us; speedup 1.0000x reference)
//
#include <hip/hip_runtime.h>
#include <cstdint>
#include <cstddef>

// ClusterProtoNetwork: single merged encoder GEMM (support rows: bf16 2-split
// 3-product MFMA; query rows: 1-product, tolerance-driven) -> per-class
// Gram-space Lloyd kmeans (100 iters, incremental fp32 S updates, f64-exact
// diagonal) -> protos -> cdist.  JAX threefry (partitionable) on-device.

typedef __attribute__((ext_vector_type(4))) float f32x4;
typedef __attribute__((ext_vector_type(8))) short s16x8;
typedef __attribute__((ext_vector_type(4))) short s16x4;
typedef __attribute__((ext_vector_type(8))) __bf16 bf16x8;

__device__ __forceinline__ unsigned short f2bf(float f) {
  unsigned u = __float_as_uint(f);
  return (unsigned short)((u + 0x7FFFu + ((u >> 16) & 1u)) >> 16);  // RTNE
}
__device__ __forceinline__ float bf2f(unsigned short h) {
  return __uint_as_float(((unsigned)h) << 16);
}

typedef const __attribute__((address_space(1))) void GV;
typedef __attribute__((address_space(3))) void LV;
__device__ __forceinline__ void gload_lds16(const void* g, void* l) {
  __builtin_amdgcn_global_load_lds((GV*)g, (LV*)l, 16, 0, 0);
}
__device__ __forceinline__ f32x4 mfma16(bf16x8 a, bf16x8 b, f32x4 c) {
  return __builtin_amdgcn_mfma_f32_16x16x32_bf16(a, b, c, 0, 0, 0);
}
__device__ __forceinline__ float wave_sum(float v) {
#pragma unroll
  for (int st = 1; st < 64; st <<= 1) v += __shfl_xor(v, st);
  return v;
}

// ---------------- Threefry-2x32 (JAX-exact, 20 rounds) ----------------
__device__ __forceinline__ void tf2x32(unsigned k0, unsigned k1, unsigned x0,
                                       unsigned x1, unsigned& y0, unsigned& y1) {
  unsigned ks0 = k0, ks1 = k1, ks2 = k0 ^ k1 ^ 0x1BD11BDAu;
  x0 += ks0; x1 += ks1;
  const int rA[4] = {13, 15, 26, 6};
  const int rB[4] = {17, 29, 16, 24};
#define ROTL(v, d) (((v) << (d)) | ((v) >> (32 - (d))))
#define RG(R)                                     \
  _Pragma("unroll") for (int i = 0; i < 4; i++) { \
    x0 += x1; x1 = ROTL(x1, R[i]); x1 ^= x0;      \
  }
  RG(rA); x0 += ks1; x1 += ks2 + 1u;
  RG(rB); x0 += ks2; x1 += ks0 + 2u;
  RG(rA); x0 += ks0; x1 += ks1 + 3u;
  RG(rB); x0 += ks1; x1 += ks2 + 4u;
  RG(rA); x0 += ks2; x1 += ks0 + 5u;
#undef RG
#undef ROTL
  y0 = x0; y1 = x1;
}

// ---------------- 1. W -> Whi^T / Wlo^T (bf16 split, transposed) -----------
__global__ __launch_bounds__(256) void prepw_k(const float* __restrict__ W,
                                               short* __restrict__ WhiT,
                                               short* __restrict__ WloT) {
  int bk = blockIdx.x, bn = blockIdx.y;  // 64 k-tiles x 16 n-tiles of 64x64
  __shared__ float tile[64][65];
  int t = threadIdx.x;
#pragma unroll
  for (int i = 0; i < 4; i++) {
    int row = i * 16 + (t >> 4);
    int col = (t & 15) * 4;
    f32x4 v = *(const f32x4*)(W + (size_t)(bk * 64 + row) * 1024 + bn * 64 + col);
    tile[row][col + 0] = v[0]; tile[row][col + 1] = v[1];
    tile[row][col + 2] = v[2]; tile[row][col + 3] = v[3];
  }
  __syncthreads();
#pragma unroll
  for (int i = 0; i < 4; i++) {
    int nrow = i * 16 + (t >> 4);
    int kcol = (t & 15) * 4;
    s16x4 hv, lv;
#pragma unroll
    for (int e = 0; e < 4; e++) {
      float v = tile[kcol + e][nrow];
      unsigned short h = f2bf(v);
      float hf = bf2f(h);
      hv[e] = (short)h;
      lv[e] = (short)f2bf(v - hf);
    }
    size_t off = (size_t)(bn * 64 + nrow) * 4096 + bk * 64 + kcol;
    *(s16x4*)(WhiT + off) = hv;
    *(s16x4*)(WloT + off) = lv;
  }
}

// ---- 2. merged encoder GEMM: emb = [sup;qry] @ W + b ----------------------
// 768 blocks (2/CU co-resident), bm<32 -> support rows, 2-split 3-product;
// bm>=32 -> query rows, 1-product (cdist tolerance >> bf16 error).
__global__ __launch_bounds__(256) void gemm_all_k(
    const float* __restrict__ sup, const float* __restrict__ qry,
    const short* __restrict__ WhiT, const short* __restrict__ WloT,
    const float* __restrict__ bias, float* __restrict__ emb) {
  __shared__ short lds[4 * 128 * 64];  // 64 KiB: Ah, Al, Bh, Bl [128][64]
  short* Ah = lds;
  short* Al = lds + 8192;
  short* Bh = lds + 16384;
  short* Bl = lds + 24576;
  const int bid = blockIdx.x;
  // XCD-sharing decode: bn-siblings differ by 96 in bid (96%8==0 -> same XCD)
  const int bm = bid % 96, bn = bid / 96;
  const bool is_sup = bm < 32;
  const int t = threadIdx.x, lane = t & 63, w = t >> 6;
  const int wr = w >> 1, wc = w & 1;
  const int fr = lane & 15, kg = lane >> 4;
  const float* Abase = is_sup ? (sup + (size_t)bm * 128 * 4096)
                              : (qry + (size_t)(bm - 32) * 128 * 4096);
  f32x4 acc[4][4] = {};
  const int ls = lane >> 3;  // 0..7
  const int lc = lane & 7;   // 0..7

  for (int kt = 0; kt < 64; ++kt) {
    const int k0 = kt * 64;
    __syncthreads();
    // A staging: fp32 -> hi (+lo if sup) bf16, XOR-swizzled 16B chunks
#pragma unroll
    for (int i = 0; i < 4; i++) {
      int row = i * 32 + w * 8 + ls;
      const float* src = Abase + (size_t)row * 4096 + k0 + lc * 8;
      f32x4 v0 = *(const f32x4*)src;
      f32x4 v1 = *(const f32x4*)(src + 4);
      s16x8 hs;
#pragma unroll
      for (int e = 0; e < 4; e++) hs[e] = (short)f2bf(v0[e]);
#pragma unroll
      for (int e = 0; e < 4; e++) hs[4 + e] = (short)f2bf(v1[e]);
      int chunk = lc ^ (row & 7);
      *(s16x8*)(Ah + row * 64 + chunk * 8) = hs;
      if (is_sup) {
        s16x8 lsv;
#pragma unroll
        for (int e = 0; e < 4; e++)
          lsv[e] = (short)f2bf(v0[e] - bf2f((unsigned short)hs[e]));
#pragma unroll
        for (int e = 0; e < 4; e++)
          lsv[4 + e] = (short)f2bf(v1[e] - bf2f((unsigned short)hs[4 + e]));
        *(s16x8*)(Al + row * 64 + chunk * 8) = lsv;
      }
    }
    // B staging: global_load_lds, swizzle via permuted per-lane source
#pragma unroll
    for (int j = 0; j < 4; j++) {
      int rowl = w * 32 + j * 8 + ls;
      int cch = (lc ^ (ls & 7)) * 8;
      size_t goff = (size_t)(bn * 128 + rowl) * 4096 + k0 + cch;
      gload_lds16(WhiT + goff, Bh + (w * 32 + j * 8) * 64);
      if (is_sup) gload_lds16(WloT + goff, Bl + (w * 32 + j * 8) * 64);
    }
    __syncthreads();
#pragma unroll
    for (int ks = 0; ks < 2; ++ks) {
      const int cx = ((ks * 4 + kg) ^ (fr & 7)) * 8;
      bf16x8 ahf[4], bhf[4];
#pragma unroll
      for (int mi = 0; mi < 4; mi++) {
        int arow = wr * 64 + mi * 16 + fr;
        ahf[mi] = __builtin_bit_cast(bf16x8, *(const s16x8*)(Ah + arow * 64 + cx));
      }
#pragma unroll
      for (int ni = 0; ni < 4; ni++) {
        int brow = wc * 64 + ni * 16 + fr;
        bhf[ni] = __builtin_bit_cast(bf16x8, *(const s16x8*)(Bh + brow * 64 + cx));
      }
      if (is_sup) {
        bf16x8 alf[4], blf[4];
#pragma unroll
        for (int mi = 0; mi < 4; mi++) {
          int arow = wr * 64 + mi * 16 + fr;
          alf[mi] =
              __builtin_bit_cast(bf16x8, *(const s16x8*)(Al + arow * 64 + cx));
        }
#pragma unroll
        for (int ni = 0; ni < 4; ni++) {
          int brow = wc * 64 + ni * 16 + fr;
          blf[ni] =
              __builtin_bit_cast(bf16x8, *(const s16x8*)(Bl + brow * 64 + cx));
        }
#pragma unroll
        for (int mi = 0; mi < 4; mi++)
#pragma unroll
          for (int ni = 0; ni < 4; ni++) {
            acc[mi][ni] = mfma16(ahf[mi], bhf[ni], acc[mi][ni]);
            acc[mi][ni] = mfma16(ahf[mi], blf[ni], acc[mi][ni]);
            acc[mi][ni] = mfma16(alf[mi], bhf[ni], acc[mi][ni]);
          }
      } else {
#pragma unroll
        for (int mi = 0; mi < 4; mi++)
#pragma unroll
          for (int ni = 0; ni < 4; ni++)
            acc[mi][ni] = mfma16(ahf[mi], bhf[ni], acc[mi][ni]);
      }
    }
  }
#pragma unroll
  for (int ni = 0; ni < 4; ni++) {
    int gc = bn * 128 + wc * 64 + ni * 16 + fr;
    float bv = bias[gc];
#pragma unroll
    for (int mi = 0; mi < 4; mi++) {
      int gr = bm * 128 + wr * 64 + mi * 16 + kg * 4;
#pragma unroll
      for (int r = 0; r < 4; r++)
        emb[(size_t)(gr + r) * 1024 + gc] = acc[mi][ni][r] + bv;
    }
  }
}

// ---------------- 3. per-class Gram G = S S^T (fp32 vector) ----------------
__global__ __launch_bounds__(256) void gram_k(const float* __restrict__ emb,
                                              float* __restrict__ G) {
  int c = blockIdx.x >> 4, tl = blockIdx.x & 15, ti = tl >> 2, tj = tl & 3;
  __shared__ float As[64][36];
  __shared__ float Bs[32][68];
  int t = threadIdx.x, ty = t >> 4, tx = t & 15;
  const float* base = emb + (size_t)c * 256 * 1024;
  float acc[4][4] = {};
  for (int k0 = 0; k0 < 1024; k0 += 32) {
    __syncthreads();
    {
      int r = t >> 2, seg = t & 3;
      const float* pa = base + (size_t)(ti * 64 + r) * 1024 + k0 + seg * 8;
      f32x4 va0 = *(const f32x4*)pa, va1 = *(const f32x4*)(pa + 4);
      *(f32x4*)(&As[r][seg * 8]) = va0;
      *(f32x4*)(&As[r][seg * 8 + 4]) = va1;
      const float* pb = base + (size_t)(tj * 64 + r) * 1024 + k0 + seg * 8;
      f32x4 vb0 = *(const f32x4*)pb, vb1 = *(const f32x4*)(pb + 4);
#pragma unroll
      for (int e = 0; e < 4; e++) Bs[seg * 8 + e][r] = vb0[e];
#pragma unroll
      for (int e = 0; e < 4; e++) Bs[seg * 8 + 4 + e][r] = vb1[e];
    }
    __syncthreads();
#pragma unroll 4
    for (int kk = 0; kk < 32; kk++) {
      float a0 = As[ty * 4 + 0][kk], a1 = As[ty * 4 + 1][kk];
      float a2 = As[ty * 4 + 2][kk], a3 = As[ty * 4 + 3][kk];
      f32x4 bv = *(const f32x4*)(&Bs[kk][tx * 4]);
#pragma unroll
      for (int jdx = 0; jdx < 4; jdx++) {
        acc[0][jdx] = fmaf(a0, bv[jdx], acc[0][jdx]);
        acc[1][jdx] = fmaf(a1, bv[jdx], acc[1][jdx]);
        acc[2][jdx] = fmaf(a2, bv[jdx], acc[2][jdx]);
        acc[3][jdx] = fmaf(a3, bv[jdx], acc[3][jdx]);
      }
    }
  }
#pragma unroll
  for (int i = 0; i < 4; i++) {
    int gr = ti * 64 + ty * 4 + i;
#pragma unroll
    for (int j = 0; j < 4; j++)
      G[(size_t)c * 65536 + (size_t)gr * 256 + tj * 64 + tx * 4 + j] = acc[i][j];
  }
}

// ---------------- 3b. overwrite G diagonal with f64-exact |x_i|^2 ----------
__global__ __launch_bounds__(256) void diag_k(const float* __restrict__ emb,
                                              float* __restrict__ G) {
  int r = blockIdx.x * 4 + (threadIdx.x >> 6);  // support row 0..4095
  int lane = threadIdx.x & 63;
  const float* x = emb + (size_t)r * 1024;
  double acc = 0.0;
#pragma unroll
  for (int ch = 0; ch < 16; ch++) {
    float v = x[ch * 64 + lane];
    acc = fma((double)v, (double)v, acc);
  }
#pragma unroll
  for (int st = 1; st < 64; st <<= 1) acc += __shfl_xor(acc, st);
  if (lane == 0) {
    int c = r >> 8, i = r & 255;
    G[(size_t)c * 65536 + (size_t)i * 256 + i] = (float)acc;
  }
}

// -------- 4. per-class kmeans, incremental fp32 S updates (100 iters) ------
__global__ __launch_bounds__(256) void kmeans2_k(const float* __restrict__ G,
                                                 float* __restrict__ wts) {
  const int c = blockIdx.x;
  const int t = threadIdx.x, lane = t & 63, w = t >> 6;
  __shared__ unsigned dmL[256], nmL[256];
  __shared__ unsigned short chg[256];
  __shared__ unsigned sk[256];
  __shared__ unsigned idx5[5];
  __shared__ float Tpart[4][5], Tu[5], C2[5], Minv[5];
  __shared__ int Hp[4][5], Ncnt[5], cntW[4];

  // --- RNG (threefry PARTITIONABLE mode, JAX >= 0.4.36 default)
  {
    unsigned o0, o1, s0k, s1k, y0, y1;
    tf2x32(0u, 42u, 0u, (unsigned)c, o0, o1);
    tf2x32(o0, o1, 0u, 1u, s0k, s1k);
    tf2x32(s0k, s1k, 0u, (unsigned)t, y0, y1);
    sk[t] = y0 ^ y1;
  }
  __syncthreads();
  {
    unsigned kt_ = sk[t];
    int rank = 0;
    for (int j = 0; j < 256; j++) {
      unsigned kj = sk[j];
      rank += (kj < kt_ || (kj == kt_ && j < t)) ? 1 : 0;
    }
    if (rank < 5) idx5[rank] = (unsigned)t;  // stable sort -> first 5 of perm
  }
  if (t < 5) Minv[t] = 1.0f;
  __syncthreads();

  unsigned m = 0;
#pragma unroll
  for (int k = 0; k < 5; k++) m |= (idx5[k] == (unsigned)t) ? (1u << k) : 0u;

  const float* Gc = G + (size_t)c * 65536;
  float s0 = Gc[(size_t)idx5[0] * 256 + t];
  float s1 = Gc[(size_t)idx5[1] * 256 + t];
  float s2 = Gc[(size_t)idx5[2] * 256 + t];
  float s3 = Gc[(size_t)idx5[3] * 256 + t];
  float s4 = Gc[(size_t)idx5[4] * 256 + t];

  for (int it = 0; it < 100; ++it) {
    float v0 = (m & 1u) ? s0 : 0.0f;
    float v1 = (m & 2u) ? s1 : 0.0f;
    float v2 = (m & 4u) ? s2 : 0.0f;
    float v3 = (m & 8u) ? s3 : 0.0f;
    float v4 = (m & 16u) ? s4 : 0.0f;
#pragma unroll
    for (int st = 1; st < 64; st <<= 1) {
      v0 += __shfl_xor(v0, st); v1 += __shfl_xor(v1, st);
      v2 += __shfl_xor(v2, st); v3 += __shfl_xor(v3, st);
      v4 += __shfl_xor(v4, st);
    }
    if (lane == 0) {
      Tpart[w][0] = v0; Tpart[w][1] = v1; Tpart[w][2] = v2;
      Tpart[w][3] = v3; Tpart[w][4] = v4;
    }
    __syncthreads();
    if (t < 5) {
      float T = Tpart[0][t] + Tpart[1][t] + Tpart[2][t] + Tpart[3][t];
      float iv = Minv[t];
      Tu[t] = T * iv * iv;   // |c_k|^2
      C2[t] = -2.0f * iv;    // coefficient on S
    }
    __syncthreads();
    float d0 = fmaf(C2[0], s0, Tu[0]);
    float d1 = fmaf(C2[1], s1, Tu[1]);
    float d2 = fmaf(C2[2], s2, Tu[2]);
    float d3 = fmaf(C2[3], s3, Tu[3]);
    float d4 = fmaf(C2[4], s4, Tu[4]);
    int a_t = 0;
    float dmn = d0;
    if (d1 < dmn) { dmn = d1; a_t = 1; }
    if (d2 < dmn) { dmn = d2; a_t = 2; }
    if (d3 < dmn) { dmn = d3; a_t = 3; }
    if (d4 < dmn) { dmn = d4; a_t = 4; }
#pragma unroll
    for (int k = 0; k < 5; k++) {
      unsigned long long bal = __ballot(a_t == k);
      if (lane == 0) Hp[w][k] = (int)__popcll(bal);
    }
    __syncthreads();
    if (t < 5) Ncnt[t] = Hp[0][t] + Hp[1][t] + Hp[2][t] + Hp[3][t];
    __syncthreads();
    unsigned nm = 0;
#pragma unroll
    for (int k = 0; k < 5; k++) {
      int bit = (Ncnt[k] > 0) ? (a_t == k ? 1 : 0) : (int)((m >> k) & 1u);
      nm |= ((unsigned)bit) << k;
    }
    unsigned dmb = nm ^ m;
    unsigned long long bal = __ballot(dmb != 0);
    int myrank = (int)__popcll(bal & ((1ull << lane) - 1ull));
    if (lane == 0) cntW[w] = (int)__popcll(bal);
    nmL[t] = nm; dmL[t] = dmb;
    __syncthreads();
    int base = 0, ntot = 0;
#pragma unroll
    for (int ww = 0; ww < 4; ww++) {
      int cw = cntW[ww];
      if (ww < w) base += cw;
      ntot += cw;
    }
    if (ntot == 0) break;  // fixed point: remaining iterations are no-ops
    if (dmb != 0) chg[base + myrank] = (unsigned short)t;
    m = nm;
    if (t < 5 && Ncnt[t] > 0) Minv[t] = 1.0f / (float)Ncnt[t];
    __syncthreads();
    for (int p = 0; p < ntot; p += 4) {
      float g[4]; int jj[4];
#pragma unroll
      for (int q = 0; q < 4; q++) {
        int idx = p + q;
        jj[q] = (idx < ntot) ? (int)chg[idx] : -1;
        g[q] = (jj[q] >= 0) ? Gc[(size_t)jj[q] * 256 + t] : 0.0f;
      }
#pragma unroll
      for (int q = 0; q < 4; q++) {
        if (jj[q] < 0) continue;
        unsigned db = dmL[jj[q]], nb = nmL[jj[q]];
        float gv = g[q];
        if (db & 1u)  s0 += (nb & 1u)  ? gv : -gv;
        if (db & 2u)  s1 += (nb & 2u)  ? gv : -gv;
        if (db & 4u)  s2 += (nb & 4u)  ? gv : -gv;
        if (db & 8u)  s3 += (nb & 8u)  ? gv : -gv;
        if (db & 16u) s4 += (nb & 16u) ? gv : -gv;
      }
    }
    __syncthreads();
  }
  float wv = 0.0f;
#pragma unroll
  for (int k = 0; k < 5; k++)
    if ((m >> k) & 1u) wv += 0.2f * Minv[k];
  wts[c * 256 + t] = wv;
}

// ---------------- 6. class protos = weighted sum of class embeddings -------
__global__ __launch_bounds__(256) void proto_k(const float* __restrict__ emb,
                                               const float* __restrict__ wts,
                                               float* __restrict__ protos) {
  int c = blockIdx.x, t = threadIdx.x;
  __shared__ float wl[256];
  wl[t] = wts[c * 256 + t];
  __syncthreads();
  f32x4 acc = {};
  const float* base = emb + (size_t)c * 256 * 1024 + t * 4;
  for (int j = 0; j < 256; j++) {
    f32x4 v = *(const f32x4*)(base + (size_t)j * 1024);
    float wj = wl[j];
#pragma unroll
    for (int e = 0; e < 4; e++) acc[e] = fmaf(wj, v[e], acc[e]);
  }
  *(f32x4*)(protos + (size_t)c * 1024 + t * 4) = acc;
}

// ---------------- 7. output: -cdist(query_emb, protos) ---------------------
__global__ __launch_bounds__(256) void dist_k(const float* __restrict__ emb,
                                              const float* __restrict__ protos,
                                              float* __restrict__ out) {
  __shared__ float P[16 * 1024];  // 64 KiB
  int t = threadIdx.x, lane = t & 63, w = t >> 6;
#pragma unroll
  for (int i = 0; i < 16; i++) {
    int off = i * 1024 + t * 4;
    *(f32x4*)(P + off) = *(const f32x4*)(protos + off);
  }
  __syncthreads();
  float psq_keep = 0.0f;
  for (int p = 0; p < 16; p++) {
    float partial = 0.0f;
#pragma unroll
    for (int ch = 0; ch < 16; ch++) {
      float x = P[p * 1024 + ch * 64 + lane];
      partial = fmaf(x, x, partial);
    }
    partial = wave_sum(partial);
    if (lane == p) psq_keep = partial;
  }
  const float* qbase = emb + (size_t)4096 * 1024;
  int r0 = blockIdx.x * 16 + w * 4;
  for (int ri = 0; ri < 4; ri++) {
    int row = r0 + ri;
    const float* q = qbase + (size_t)row * 1024;
    float qv[16];
#pragma unroll
    for (int ch = 0; ch < 16; ch++) qv[ch] = q[ch * 64 + lane];
    float qsq = 0.0f;
#pragma unroll
    for (int ch = 0; ch < 16; ch++) qsq = fmaf(qv[ch], qv[ch], qsq);
    qsq = wave_sum(qsq);
    float dsel = 0.0f;
    for (int p = 0; p < 16; p++) {
      float dp = 0.0f;
#pragma unroll
      for (int ch = 0; ch < 16; ch++)
        dp = fmaf(qv[ch], P[p * 1024 + ch * 64 + lane], dp);
      dp = wave_sum(dp);
      if (lane == p) dsel = dp;
    }
    if (lane < 16) {
      float d2 = qsq - 2.0f * dsel + psq_keep;
      d2 = fmaxf(d2, 0.0f);
      out[(size_t)row * 16 + lane] = -sqrtf(d2);
    }
  }
}

// ---------------- launch ---------------------------------------------------
extern "C" void kernel_launch(void* const* d_in, const int* in_sizes, int n_in,
                              void* d_out, int out_size, void* d_ws,
                              size_t ws_size, hipStream_t stream) {
  const float* sup = (const float*)d_in[0];
  const float* qry = (const float*)d_in[1];
  const float* W = (const float*)d_in[2];
  const float* b = (const float*)d_in[3];
  float* out = (float*)d_out;
  char* ws = (char*)d_ws;
  short* WhiT = (short*)(ws + 0);           //  8.0 MiB
  short* WloT = (short*)(ws + 8388608);     //  8.0 MiB
  float* emb = (float*)(ws + 16777216);     // 48.0 MiB [12288][1024]
  float* G = (float*)(ws + 67108864);       //  4.0 MiB
  float* wts = (float*)(ws + 71303168);     // 16 KiB
  float* protos = (float*)(ws + 71319552);  // 64 KiB
  (void)in_sizes; (void)n_in; (void)out_size; (void)ws_size;

  prepw_k<<<dim3(64, 16), 256, 0, stream>>>(W, WhiT, WloT);
  gemm_all_k<<<768, 256, 0, stream>>>(sup, qry, WhiT, WloT, b, emb);
  gram_k<<<256, 256, 0, stream>>>(emb, G);
  diag_k<<<1024, 256, 0, stream>>>(emb, G);
  kmeans2_k<<<16, 256, 0, stream>>>(G, wts);
  proto_k<<<16, 256, 0, stream>>>(emb, wts, protos);
  dist_k<<<512, 256, 0, stream>>>(emb, protos, out);
}

// Round 7
// 501.685 us; speedup vs baseline: 1.1753x; 1.1753x over previous
//
#include <hip/hip_runtime.h>
#include <cstdint>
#include <cstddef>

// ClusterProtoNetwork: pre-converted bf16 operands (A hi/lo, W hi/lo) ->
// all-gload_lds encoder GEMM (sup rows 3-product, qry rows 1-product) ->
// per-class Gram-space Lloyd kmeans (incremental fp32) -> protos -> cdist.
// Fallback in-loop-convert GEMM if workspace < 196 MB.

typedef __attribute__((ext_vector_type(4))) float f32x4;
typedef __attribute__((ext_vector_type(8))) short s16x8;
typedef __attribute__((ext_vector_type(4))) short s16x4;
typedef __attribute__((ext_vector_type(8))) __bf16 bf16x8;

__device__ __forceinline__ unsigned short f2bf(float f) {
  unsigned u = __float_as_uint(f);
  return (unsigned short)((u + 0x7FFFu + ((u >> 16) & 1u)) >> 16);  // RTNE
}
__device__ __forceinline__ float bf2f(unsigned short h) {
  return __uint_as_float(((unsigned)h) << 16);
}

typedef const __attribute__((address_space(1))) void GV;
typedef __attribute__((address_space(3))) void LV;
__device__ __forceinline__ void gload_lds16(const void* g, void* l) {
  __builtin_amdgcn_global_load_lds((GV*)g, (LV*)l, 16, 0, 0);
}
__device__ __forceinline__ f32x4 mfma16(bf16x8 a, bf16x8 b, f32x4 c) {
  return __builtin_amdgcn_mfma_f32_16x16x32_bf16(a, b, c, 0, 0, 0);
}
__device__ __forceinline__ float wave_sum(float v) {
#pragma unroll
  for (int st = 1; st < 64; st <<= 1) v += __shfl_xor(v, st);
  return v;
}

// ---------------- Threefry-2x32 (JAX-exact, 20 rounds) ----------------
__device__ __forceinline__ void tf2x32(unsigned k0, unsigned k1, unsigned x0,
                                       unsigned x1, unsigned& y0, unsigned& y1) {
  unsigned ks0 = k0, ks1 = k1, ks2 = k0 ^ k1 ^ 0x1BD11BDAu;
  x0 += ks0; x1 += ks1;
  const int rA[4] = {13, 15, 26, 6};
  const int rB[4] = {17, 29, 16, 24};
#define ROTL(v, d) (((v) << (d)) | ((v) >> (32 - (d))))
#define RG(R)                                     \
  _Pragma("unroll") for (int i = 0; i < 4; i++) { \
    x0 += x1; x1 = ROTL(x1, R[i]); x1 ^= x0;      \
  }
  RG(rA); x0 += ks1; x1 += ks2 + 1u;
  RG(rB); x0 += ks2; x1 += ks0 + 2u;
  RG(rA); x0 += ks0; x1 += ks1 + 3u;
  RG(rB); x0 += ks1; x1 += ks2 + 4u;
  RG(rA); x0 += ks2; x1 += ks0 + 5u;
#undef RG
#undef ROTL
  y0 = x0; y1 = x1;
}

// ---------------- 1. W -> Whi^T / Wlo^T (bf16 split, transposed) -----------
__global__ __launch_bounds__(256) void prepw_k(const float* __restrict__ W,
                                               short* __restrict__ WhiT,
                                               short* __restrict__ WloT) {
  int bk = blockIdx.x, bn = blockIdx.y;  // 64 k-tiles x 16 n-tiles of 64x64
  __shared__ float tile[64][65];
  int t = threadIdx.x;
#pragma unroll
  for (int i = 0; i < 4; i++) {
    int row = i * 16 + (t >> 4);
    int col = (t & 15) * 4;
    f32x4 v = *(const f32x4*)(W + (size_t)(bk * 64 + row) * 1024 + bn * 64 + col);
    tile[row][col + 0] = v[0]; tile[row][col + 1] = v[1];
    tile[row][col + 2] = v[2]; tile[row][col + 3] = v[3];
  }
  __syncthreads();
#pragma unroll
  for (int i = 0; i < 4; i++) {
    int nrow = i * 16 + (t >> 4);
    int kcol = (t & 15) * 4;
    s16x4 hv, lv;
#pragma unroll
    for (int e = 0; e < 4; e++) {
      float v = tile[kcol + e][nrow];
      unsigned short h = f2bf(v);
      float hf = bf2f(h);
      hv[e] = (short)h;
      lv[e] = (short)f2bf(v - hf);
    }
    size_t off = (size_t)(bn * 64 + nrow) * 4096 + bk * 64 + kcol;
    *(s16x4*)(WhiT + off) = hv;
    *(s16x4*)(WloT + off) = lv;
  }
}

// ------- 1b. A pre-convert: sup -> Shi/Slo, qry -> Qhi (row-major bf16) ----
__global__ __launch_bounds__(256) void prepa_k(const float* __restrict__ sup,
                                               const float* __restrict__ qry,
                                               short* __restrict__ Shi,
                                               short* __restrict__ Slo,
                                               short* __restrict__ Qhi) {
  size_t gid = (size_t)blockIdx.x * 256 + threadIdx.x;  // one 8-elem chunk
  const size_t sup_n8 = (size_t)4096 * 4096 / 8;        // 2M chunks
  if (gid < sup_n8) {
    const float* src = sup + gid * 8;
    f32x4 v0 = *(const f32x4*)src, v1 = *(const f32x4*)(src + 4);
    s16x8 h, l;
#pragma unroll
    for (int e = 0; e < 4; e++) {
      unsigned short hh = f2bf(v0[e]);
      h[e] = (short)hh; l[e] = (short)f2bf(v0[e] - bf2f(hh));
    }
#pragma unroll
    for (int e = 0; e < 4; e++) {
      unsigned short hh = f2bf(v1[e]);
      h[4 + e] = (short)hh; l[4 + e] = (short)f2bf(v1[e] - bf2f(hh));
    }
    *(s16x8*)(Shi + gid * 8) = h;
    *(s16x8*)(Slo + gid * 8) = l;
  } else {
    size_t q = gid - sup_n8;  // < 4M chunks
    const float* src = qry + q * 8;
    f32x4 v0 = *(const f32x4*)src, v1 = *(const f32x4*)(src + 4);
    s16x8 h;
#pragma unroll
    for (int e = 0; e < 4; e++) h[e] = (short)f2bf(v0[e]);
#pragma unroll
    for (int e = 0; e < 4; e++) h[4 + e] = (short)f2bf(v1[e]);
    *(s16x8*)(Qhi + q * 8) = h;
  }
}

// ---- 2. fast GEMM: all operands bf16 in HBM, staged via global_load_lds ---
// 768 blocks; bm<32 -> support (3-product hi/lo), else query (1-product).
__global__ __launch_bounds__(256) void gemm_fast_k(
    const short* __restrict__ Shi, const short* __restrict__ Slo,
    const short* __restrict__ Qhi, const short* __restrict__ WhiT,
    const short* __restrict__ WloT, const float* __restrict__ bias,
    float* __restrict__ emb) {
  __shared__ short lds[4 * 128 * 64];  // 64 KiB: Ah, Al, Bh, Bl [128][64]
  short* Ah = lds;
  short* Al = lds + 8192;
  short* Bh = lds + 16384;
  short* Bl = lds + 24576;
  const int bid = blockIdx.x;
  // XCD-sharing decode: bn-siblings differ by 96 (96%8==0 -> same XCD L2)
  const int bm = bid % 96, bn = bid / 96;
  const bool is_sup = bm < 32;
  const int t = threadIdx.x, lane = t & 63, w = t >> 6;
  const int wr = w >> 1, wc = w & 1;
  const int fr = lane & 15, kg = lane >> 4;
  const short* Ag = is_sup ? (Shi + (size_t)bm * 128 * 4096)
                           : (Qhi + (size_t)(bm - 32) * 128 * 4096);
  const short* Alg = Slo + (size_t)bm * 128 * 4096;  // deref'd only if sup
  f32x4 acc[4][4] = {};
  const int ls = lane >> 3;  // 0..7
  const int lc = lane & 7;   // 0..7

  for (int kt = 0; kt < 64; ++kt) {
    const int k0 = kt * 64;
    __syncthreads();
    // stage A,B (hi, + lo if sup): linear LDS dest + inverse-swizzled source
#pragma unroll
    for (int j = 0; j < 4; j++) {
      int rowl = w * 32 + j * 8 + ls;
      int cch = (lc ^ (ls & 7)) * 8;
      size_t aoff = (size_t)rowl * 4096 + k0 + cch;
      size_t boff = (size_t)(bn * 128 + rowl) * 4096 + k0 + cch;
      int ldst = (w * 32 + j * 8) * 64;
      gload_lds16(Ag + aoff, Ah + ldst);
      gload_lds16(WhiT + boff, Bh + ldst);
      if (is_sup) {
        gload_lds16(Alg + aoff, Al + ldst);
        gload_lds16(WloT + boff, Bl + ldst);
      }
    }
    __syncthreads();
#pragma unroll
    for (int ks = 0; ks < 2; ++ks) {
      const int cx = ((ks * 4 + kg) ^ (fr & 7)) * 8;
      bf16x8 ahf[4], bhf[4];
#pragma unroll
      for (int mi = 0; mi < 4; mi++) {
        int arow = wr * 64 + mi * 16 + fr;
        ahf[mi] = __builtin_bit_cast(bf16x8, *(const s16x8*)(Ah + arow * 64 + cx));
      }
#pragma unroll
      for (int ni = 0; ni < 4; ni++) {
        int brow = wc * 64 + ni * 16 + fr;
        bhf[ni] = __builtin_bit_cast(bf16x8, *(const s16x8*)(Bh + brow * 64 + cx));
      }
      if (is_sup) {
        bf16x8 alf[4], blf[4];
#pragma unroll
        for (int mi = 0; mi < 4; mi++) {
          int arow = wr * 64 + mi * 16 + fr;
          alf[mi] =
              __builtin_bit_cast(bf16x8, *(const s16x8*)(Al + arow * 64 + cx));
        }
#pragma unroll
        for (int ni = 0; ni < 4; ni++) {
          int brow = wc * 64 + ni * 16 + fr;
          blf[ni] =
              __builtin_bit_cast(bf16x8, *(const s16x8*)(Bl + brow * 64 + cx));
        }
#pragma unroll
        for (int mi = 0; mi < 4; mi++)
#pragma unroll
          for (int ni = 0; ni < 4; ni++) {
            acc[mi][ni] = mfma16(ahf[mi], bhf[ni], acc[mi][ni]);
            acc[mi][ni] = mfma16(ahf[mi], blf[ni], acc[mi][ni]);
            acc[mi][ni] = mfma16(alf[mi], bhf[ni], acc[mi][ni]);
          }
      } else {
#pragma unroll
        for (int mi = 0; mi < 4; mi++)
#pragma unroll
          for (int ni = 0; ni < 4; ni++)
            acc[mi][ni] = mfma16(ahf[mi], bhf[ni], acc[mi][ni]);
      }
    }
  }
#pragma unroll
  for (int ni = 0; ni < 4; ni++) {
    int gc = bn * 128 + wc * 64 + ni * 16 + fr;
    float bv = bias[gc];
#pragma unroll
    for (int mi = 0; mi < 4; mi++) {
      int gr = bm * 128 + wr * 64 + mi * 16 + kg * 4;
#pragma unroll
      for (int r = 0; r < 4; r++)
        emb[(size_t)(gr + r) * 1024 + gc] = acc[mi][ni][r] + bv;
    }
  }
}

// ---- 2'. fallback GEMM (in-loop convert; used when ws too small) ----------
__global__ __launch_bounds__(256) void gemm_all_k(
    const float* __restrict__ sup, const float* __restrict__ qry,
    const short* __restrict__ WhiT, const short* __restrict__ WloT,
    const float* __restrict__ bias, float* __restrict__ emb) {
  __shared__ short lds[4 * 128 * 64];
  short* Ah = lds;
  short* Al = lds + 8192;
  short* Bh = lds + 16384;
  short* Bl = lds + 24576;
  const int bid = blockIdx.x;
  const int bm = bid % 96, bn = bid / 96;
  const bool is_sup = bm < 32;
  const int t = threadIdx.x, lane = t & 63, w = t >> 6;
  const int wr = w >> 1, wc = w & 1;
  const int fr = lane & 15, kg = lane >> 4;
  const float* Abase = is_sup ? (sup + (size_t)bm * 128 * 4096)
                              : (qry + (size_t)(bm - 32) * 128 * 4096);
  f32x4 acc[4][4] = {};
  const int ls = lane >> 3, lc = lane & 7;

  for (int kt = 0; kt < 64; ++kt) {
    const int k0 = kt * 64;
    __syncthreads();
#pragma unroll
    for (int i = 0; i < 4; i++) {
      int row = i * 32 + w * 8 + ls;
      const float* src = Abase + (size_t)row * 4096 + k0 + lc * 8;
      f32x4 v0 = *(const f32x4*)src;
      f32x4 v1 = *(const f32x4*)(src + 4);
      s16x8 hs;
#pragma unroll
      for (int e = 0; e < 4; e++) hs[e] = (short)f2bf(v0[e]);
#pragma unroll
      for (int e = 0; e < 4; e++) hs[4 + e] = (short)f2bf(v1[e]);
      int chunk = lc ^ (row & 7);
      *(s16x8*)(Ah + row * 64 + chunk * 8) = hs;
      if (is_sup) {
        s16x8 lsv;
#pragma unroll
        for (int e = 0; e < 4; e++)
          lsv[e] = (short)f2bf(v0[e] - bf2f((unsigned short)hs[e]));
#pragma unroll
        for (int e = 0; e < 4; e++)
          lsv[4 + e] = (short)f2bf(v1[e] - bf2f((unsigned short)hs[4 + e]));
        *(s16x8*)(Al + row * 64 + chunk * 8) = lsv;
      }
    }
#pragma unroll
    for (int j = 0; j < 4; j++) {
      int rowl = w * 32 + j * 8 + ls;
      int cch = (lc ^ (ls & 7)) * 8;
      size_t goff = (size_t)(bn * 128 + rowl) * 4096 + k0 + cch;
      gload_lds16(WhiT + goff, Bh + (w * 32 + j * 8) * 64);
      if (is_sup) gload_lds16(WloT + goff, Bl + (w * 32 + j * 8) * 64);
    }
    __syncthreads();
#pragma unroll
    for (int ks = 0; ks < 2; ++ks) {
      const int cx = ((ks * 4 + kg) ^ (fr & 7)) * 8;
      bf16x8 ahf[4], bhf[4];
#pragma unroll
      for (int mi = 0; mi < 4; mi++) {
        int arow = wr * 64 + mi * 16 + fr;
        ahf[mi] = __builtin_bit_cast(bf16x8, *(const s16x8*)(Ah + arow * 64 + cx));
      }
#pragma unroll
      for (int ni = 0; ni < 4; ni++) {
        int brow = wc * 64 + ni * 16 + fr;
        bhf[ni] = __builtin_bit_cast(bf16x8, *(const s16x8*)(Bh + brow * 64 + cx));
      }
      if (is_sup) {
        bf16x8 alf[4], blf[4];
#pragma unroll
        for (int mi = 0; mi < 4; mi++) {
          int arow = wr * 64 + mi * 16 + fr;
          alf[mi] =
              __builtin_bit_cast(bf16x8, *(const s16x8*)(Al + arow * 64 + cx));
        }
#pragma unroll
        for (int ni = 0; ni < 4; ni++) {
          int brow = wc * 64 + ni * 16 + fr;
          blf[ni] =
              __builtin_bit_cast(bf16x8, *(const s16x8*)(Bl + brow * 64 + cx));
        }
#pragma unroll
        for (int mi = 0; mi < 4; mi++)
#pragma unroll
          for (int ni = 0; ni < 4; ni++) {
            acc[mi][ni] = mfma16(ahf[mi], bhf[ni], acc[mi][ni]);
            acc[mi][ni] = mfma16(ahf[mi], blf[ni], acc[mi][ni]);
            acc[mi][ni] = mfma16(alf[mi], bhf[ni], acc[mi][ni]);
          }
      } else {
#pragma unroll
        for (int mi = 0; mi < 4; mi++)
#pragma unroll
          for (int ni = 0; ni < 4; ni++)
            acc[mi][ni] = mfma16(ahf[mi], bhf[ni], acc[mi][ni]);
      }
    }
  }
#pragma unroll
  for (int ni = 0; ni < 4; ni++) {
    int gc = bn * 128 + wc * 64 + ni * 16 + fr;
    float bv = bias[gc];
#pragma unroll
    for (int mi = 0; mi < 4; mi++) {
      int gr = bm * 128 + wr * 64 + mi * 16 + kg * 4;
#pragma unroll
      for (int r = 0; r < 4; r++)
        emb[(size_t)(gr + r) * 1024 + gc] = acc[mi][ni][r] + bv;
    }
  }
}

// ---------------- 3. per-class Gram G = S S^T (fp32 vector) ----------------
__global__ __launch_bounds__(256) void gram_k(const float* __restrict__ emb,
                                              float* __restrict__ G) {
  int c = blockIdx.x >> 4, tl = blockIdx.x & 15, ti = tl >> 2, tj = tl & 3;
  __shared__ float As[64][36];
  __shared__ float Bs[32][68];
  int t = threadIdx.x, ty = t >> 4, tx = t & 15;
  const float* base = emb + (size_t)c * 256 * 1024;
  float acc[4][4] = {};
  for (int k0 = 0; k0 < 1024; k0 += 32) {
    __syncthreads();
    {
      int r = t >> 2, seg = t & 3;
      const float* pa = base + (size_t)(ti * 64 + r) * 1024 + k0 + seg * 8;
      f32x4 va0 = *(const f32x4*)pa, va1 = *(const f32x4*)(pa + 4);
      *(f32x4*)(&As[r][seg * 8]) = va0;
      *(f32x4*)(&As[r][seg * 8 + 4]) = va1;
      const float* pb = base + (size_t)(tj * 64 + r) * 1024 + k0 + seg * 8;
      f32x4 vb0 = *(const f32x4*)pb, vb1 = *(const f32x4*)(pb + 4);
#pragma unroll
      for (int e = 0; e < 4; e++) Bs[seg * 8 + e][r] = vb0[e];
#pragma unroll
      for (int e = 0; e < 4; e++) Bs[seg * 8 + 4 + e][r] = vb1[e];
    }
    __syncthreads();
#pragma unroll 4
    for (int kk = 0; kk < 32; kk++) {
      float a0 = As[ty * 4 + 0][kk], a1 = As[ty * 4 + 1][kk];
      float a2 = As[ty * 4 + 2][kk], a3 = As[ty * 4 + 3][kk];
      f32x4 bv = *(const f32x4*)(&Bs[kk][tx * 4]);
#pragma unroll
      for (int jdx = 0; jdx < 4; jdx++) {
        acc[0][jdx] = fmaf(a0, bv[jdx], acc[0][jdx]);
        acc[1][jdx] = fmaf(a1, bv[jdx], acc[1][jdx]);
        acc[2][jdx] = fmaf(a2, bv[jdx], acc[2][jdx]);
        acc[3][jdx] = fmaf(a3, bv[jdx], acc[3][jdx]);
      }
    }
  }
#pragma unroll
  for (int i = 0; i < 4; i++) {
    int gr = ti * 64 + ty * 4 + i;
#pragma unroll
    for (int j = 0; j < 4; j++)
      G[(size_t)c * 65536 + (size_t)gr * 256 + tj * 64 + tx * 4 + j] = acc[i][j];
  }
}

// ---------------- 3b. overwrite G diagonal with f64-exact |x_i|^2 ----------
__global__ __launch_bounds__(256) void diag_k(const float* __restrict__ emb,
                                              float* __restrict__ G) {
  int r = blockIdx.x * 4 + (threadIdx.x >> 6);  // support row 0..4095
  int lane = threadIdx.x & 63;
  const float* x = emb + (size_t)r * 1024;
  double acc = 0.0;
#pragma unroll
  for (int ch = 0; ch < 16; ch++) {
    float v = x[ch * 64 + lane];
    acc = fma((double)v, (double)v, acc);
  }
#pragma unroll
  for (int st = 1; st < 64; st <<= 1) acc += __shfl_xor(acc, st);
  if (lane == 0) {
    int c = r >> 8, i = r & 255;
    G[(size_t)c * 65536 + (size_t)i * 256 + i] = (float)acc;
  }
}

// -------- 4. per-class kmeans, incremental fp32 S updates (100 iters) ------
__global__ __launch_bounds__(256) void kmeans2_k(const float* __restrict__ G,
                                                 float* __restrict__ wts) {
  const int c = blockIdx.x;
  const int t = threadIdx.x, lane = t & 63, w = t >> 6;
  __shared__ unsigned dmL[256], nmL[256];
  __shared__ unsigned short chg[256];
  __shared__ unsigned sk[256];
  __shared__ unsigned idx5[5];
  __shared__ float Tpart[4][5], Tu[5], C2[5], Minv[5];
  __shared__ int Hp[4][5], Ncnt[5], cntW[4];

  // --- RNG (threefry PARTITIONABLE mode, JAX >= 0.4.36 default)
  {
    unsigned o0, o1, s0k, s1k, y0, y1;
    tf2x32(0u, 42u, 0u, (unsigned)c, o0, o1);
    tf2x32(o0, o1, 0u, 1u, s0k, s1k);
    tf2x32(s0k, s1k, 0u, (unsigned)t, y0, y1);
    sk[t] = y0 ^ y1;
  }
  __syncthreads();
  {
    unsigned kt_ = sk[t];
    int rank = 0;
    for (int j = 0; j < 256; j++) {
      unsigned kj = sk[j];
      rank += (kj < kt_ || (kj == kt_ && j < t)) ? 1 : 0;
    }
    if (rank < 5) idx5[rank] = (unsigned)t;  // stable sort -> first 5 of perm
  }
  if (t < 5) Minv[t] = 1.0f;
  __syncthreads();

  unsigned m = 0;
#pragma unroll
  for (int k = 0; k < 5; k++) m |= (idx5[k] == (unsigned)t) ? (1u << k) : 0u;

  const float* Gc = G + (size_t)c * 65536;
  float s0 = Gc[(size_t)idx5[0] * 256 + t];
  float s1 = Gc[(size_t)idx5[1] * 256 + t];
  float s2 = Gc[(size_t)idx5[2] * 256 + t];
  float s3 = Gc[(size_t)idx5[3] * 256 + t];
  float s4 = Gc[(size_t)idx5[4] * 256 + t];

  for (int it = 0; it < 100; ++it) {
    float v0 = (m & 1u) ? s0 : 0.0f;
    float v1 = (m & 2u) ? s1 : 0.0f;
    float v2 = (m & 4u) ? s2 : 0.0f;
    float v3 = (m & 8u) ? s3 : 0.0f;
    float v4 = (m & 16u) ? s4 : 0.0f;
#pragma unroll
    for (int st = 1; st < 64; st <<= 1) {
      v0 += __shfl_xor(v0, st); v1 += __shfl_xor(v1, st);
      v2 += __shfl_xor(v2, st); v3 += __shfl_xor(v3, st);
      v4 += __shfl_xor(v4, st);
    }
    if (lane == 0) {
      Tpart[w][0] = v0; Tpart[w][1] = v1; Tpart[w][2] = v2;
      Tpart[w][3] = v3; Tpart[w][4] = v4;
    }
    __syncthreads();
    if (t < 5) {
      float T = Tpart[0][t] + Tpart[1][t] + Tpart[2][t] + Tpart[3][t];
      float iv = Minv[t];
      Tu[t] = T * iv * iv;   // |c_k|^2
      C2[t] = -2.0f * iv;    // coefficient on S
    }
    __syncthreads();
    float d0 = fmaf(C2[0], s0, Tu[0]);
    float d1 = fmaf(C2[1], s1, Tu[1]);
    float d2 = fmaf(C2[2], s2, Tu[2]);
    float d3 = fmaf(C2[3], s3, Tu[3]);
    float d4 = fmaf(C2[4], s4, Tu[4]);
    int a_t = 0;
    float dmn = d0;
    if (d1 < dmn) { dmn = d1; a_t = 1; }
    if (d2 < dmn) { dmn = d2; a_t = 2; }
    if (d3 < dmn) { dmn = d3; a_t = 3; }
    if (d4 < dmn) { dmn = d4; a_t = 4; }
#pragma unroll
    for (int k = 0; k < 5; k++) {
      unsigned long long bal = __ballot(a_t == k);
      if (lane == 0) Hp[w][k] = (int)__popcll(bal);
    }
    __syncthreads();
    if (t < 5) Ncnt[t] = Hp[0][t] + Hp[1][t] + Hp[2][t] + Hp[3][t];
    __syncthreads();
    unsigned nm = 0;
#pragma unroll
    for (int k = 0; k < 5; k++) {
      int bit = (Ncnt[k] > 0) ? (a_t == k ? 1 : 0) : (int)((m >> k) & 1u);
      nm |= ((unsigned)bit) << k;
    }
    unsigned dmb = nm ^ m;
    unsigned long long bal = __ballot(dmb != 0);
    int myrank = (int)__popcll(bal & ((1ull << lane) - 1ull));
    if (lane == 0) cntW[w] = (int)__popcll(bal);
    nmL[t] = nm; dmL[t] = dmb;
    __syncthreads();
    int base = 0, ntot = 0;
#pragma unroll
    for (int ww = 0; ww < 4; ww++) {
      int cw = cntW[ww];
      if (ww < w) base += cw;
      ntot += cw;
    }
    if (ntot == 0) break;  // fixed point: remaining iterations are no-ops
    if (dmb != 0) chg[base + myrank] = (unsigned short)t;
    m = nm;
    if (t < 5 && Ncnt[t] > 0) Minv[t] = 1.0f / (float)Ncnt[t];
    __syncthreads();
    for (int p = 0; p < ntot; p += 4) {
      float g[4]; int jj[4];
#pragma unroll
      for (int q = 0; q < 4; q++) {
        int idx = p + q;
        jj[q] = (idx < ntot) ? (int)chg[idx] : -1;
        g[q] = (jj[q] >= 0) ? Gc[(size_t)jj[q] * 256 + t] : 0.0f;
      }
#pragma unroll
      for (int q = 0; q < 4; q++) {
        if (jj[q] < 0) continue;
        unsigned db = dmL[jj[q]], nb = nmL[jj[q]];
        float gv = g[q];
        if (db & 1u)  s0 += (nb & 1u)  ? gv : -gv;
        if (db & 2u)  s1 += (nb & 2u)  ? gv : -gv;
        if (db & 4u)  s2 += (nb & 4u)  ? gv : -gv;
        if (db & 8u)  s3 += (nb & 8u)  ? gv : -gv;
        if (db & 16u) s4 += (nb & 16u) ? gv : -gv;
      }
    }
    __syncthreads();
  }
  float wv = 0.0f;
#pragma unroll
  for (int k = 0; k < 5; k++)
    if ((m >> k) & 1u) wv += 0.2f * Minv[k];
  wts[c * 256 + t] = wv;
}

// ---------------- 6. class protos = weighted sum of class embeddings -------
__global__ __launch_bounds__(256) void proto_k(const float* __restrict__ emb,
                                               const float* __restrict__ wts,
                                               float* __restrict__ protos) {
  int c = blockIdx.x, t = threadIdx.x;
  __shared__ float wl[256];
  wl[t] = wts[c * 256 + t];
  __syncthreads();
  f32x4 acc = {};
  const float* base = emb + (size_t)c * 256 * 1024 + t * 4;
  for (int j = 0; j < 256; j++) {
    f32x4 v = *(const f32x4*)(base + (size_t)j * 1024);
    float wj = wl[j];
#pragma unroll
    for (int e = 0; e < 4; e++) acc[e] = fmaf(wj, v[e], acc[e]);
  }
  *(f32x4*)(protos + (size_t)c * 1024 + t * 4) = acc;
}

// ---------------- 7. output: -cdist(query_emb, protos) ---------------------
__global__ __launch_bounds__(256) void dist_k(const float* __restrict__ emb,
                                              const float* __restrict__ protos,
                                              float* __restrict__ out) {
  __shared__ float P[16 * 1024];  // 64 KiB
  int t = threadIdx.x, lane = t & 63, w = t >> 6;
#pragma unroll
  for (int i = 0; i < 16; i++) {
    int off = i * 1024 + t * 4;
    *(f32x4*)(P + off) = *(const f32x4*)(protos + off);
  }
  __syncthreads();
  float psq_keep = 0.0f;
  for (int p = 0; p < 16; p++) {
    float partial = 0.0f;
#pragma unroll
    for (int ch = 0; ch < 16; ch++) {
      float x = P[p * 1024 + ch * 64 + lane];
      partial = fmaf(x, x, partial);
    }
    partial = wave_sum(partial);
    if (lane == p) psq_keep = partial;
  }
  const float* qbase = emb + (size_t)4096 * 1024;
  int r0 = blockIdx.x * 16 + w * 4;
  for (int ri = 0; ri < 4; ri++) {
    int row = r0 + ri;
    const float* q = qbase + (size_t)row * 1024;
    float qv[16];
#pragma unroll
    for (int ch = 0; ch < 16; ch++) qv[ch] = q[ch * 64 + lane];
    float qsq = 0.0f;
#pragma unroll
    for (int ch = 0; ch < 16; ch++) qsq = fmaf(qv[ch], qv[ch], qsq);
    qsq = wave_sum(qsq);
    float dsel = 0.0f;
    for (int p = 0; p < 16; p++) {
      float dp = 0.0f;
#pragma unroll
      for (int ch = 0; ch < 16; ch++)
        dp = fmaf(qv[ch], P[p * 1024 + ch * 64 + lane], dp);
      dp = wave_sum(dp);
      if (lane == p) dsel = dp;
    }
    if (lane < 16) {
      float d2 = qsq - 2.0f * dsel + psq_keep;
      d2 = fmaxf(d2, 0.0f);
      out[(size_t)row * 16 + lane] = -sqrtf(d2);
    }
  }
}

// ---------------- launch ---------------------------------------------------
extern "C" void kernel_launch(void* const* d_in, const int* in_sizes, int n_in,
                              void* d_out, int out_size, void* d_ws,
                              size_t ws_size, hipStream_t stream) {
  const float* sup = (const float*)d_in[0];
  const float* qry = (const float*)d_in[1];
  const float* W = (const float*)d_in[2];
  const float* b = (const float*)d_in[3];
  float* out = (float*)d_out;
  char* ws = (char*)d_ws;
  (void)in_sizes; (void)n_in; (void)out_size;

  const size_t NEED_FAST = 205602816ULL;  // ~196 MiB
  if (ws_size >= NEED_FAST) {
    short* WhiT = (short*)(ws + 0);            //  8 MiB
    short* WloT = (short*)(ws + 8388608);      //  8 MiB
    short* Shi = (short*)(ws + 16777216);      // 32 MiB
    short* Slo = (short*)(ws + 50331648);      // 32 MiB
    short* Qhi = (short*)(ws + 83886080);      // 64 MiB
    float* emb = (float*)(ws + 150994944);     // 48 MiB
    float* G = (float*)(ws + 201326592);       //  4 MiB
    float* wts = (float*)(ws + 205520896);     // 16 KiB
    float* protos = (float*)(ws + 205537280);  // 64 KiB

    prepw_k<<<dim3(64, 16), 256, 0, stream>>>(W, WhiT, WloT);
    prepa_k<<<24576, 256, 0, stream>>>(sup, qry, Shi, Slo, Qhi);
    gemm_fast_k<<<768, 256, 0, stream>>>(Shi, Slo, Qhi, WhiT, WloT, b, emb);
    gram_k<<<256, 256, 0, stream>>>(emb, G);
    diag_k<<<1024, 256, 0, stream>>>(emb, G);
    kmeans2_k<<<16, 256, 0, stream>>>(G, wts);
    proto_k<<<16, 256, 0, stream>>>(emb, wts, protos);
    dist_k<<<512, 256, 0, stream>>>(emb, protos, out);
  } else {
    short* WhiT = (short*)(ws + 0);
    short* WloT = (short*)(ws + 8388608);
    float* emb = (float*)(ws + 16777216);
    float* G = (float*)(ws + 67108864);
    float* wts = (float*)(ws + 71303168);
    float* protos = (float*)(ws + 71319552);

    prepw_k<<<dim3(64, 16), 256, 0, stream>>>(W, WhiT, WloT);
    gemm_all_k<<<768, 256, 0, stream>>>(sup, qry, WhiT, WloT, b, emb);
    gram_k<<<256, 256, 0, stream>>>(emb, G);
    diag_k<<<1024, 256, 0, stream>>>(emb, G);
    kmeans2_k<<<16, 256, 0, stream>>>(G, wts);
    proto_k<<<16, 256, 0, stream>>>(emb, wts, protos);
    dist_k<<<512, 256, 0, stream>>>(emb, protos, out);
  }
}

// Round 8
// 444.045 us; speedup vs baseline: 1.3278x; 1.1298x over previous
//
#include <hip/hip_runtime.h>
#include <cstdint>
#include <cstddef>

// ClusterProtoNetwork: pre-converted bf16 operands -> split encoder GEMMs
// (sup: BM=64 3-product, 3 blk/CU; qry: BM=128 1-product, 5 blk/CU) ->
// per-class Gram kmeans (incremental fp32) -> protos (2-stage) -> cdist.
// Fallback in-loop-convert GEMM if workspace too small.

typedef __attribute__((ext_vector_type(4))) float f32x4;
typedef __attribute__((ext_vector_type(8))) short s16x8;
typedef __attribute__((ext_vector_type(4))) short s16x4;
typedef __attribute__((ext_vector_type(8))) __bf16 bf16x8;

__device__ __forceinline__ unsigned short f2bf(float f) {
  unsigned u = __float_as_uint(f);
  return (unsigned short)((u + 0x7FFFu + ((u >> 16) & 1u)) >> 16);  // RTNE
}
__device__ __forceinline__ float bf2f(unsigned short h) {
  return __uint_as_float(((unsigned)h) << 16);
}

typedef const __attribute__((address_space(1))) void GV;
typedef __attribute__((address_space(3))) void LV;
__device__ __forceinline__ void gload_lds16(const void* g, void* l) {
  __builtin_amdgcn_global_load_lds((GV*)g, (LV*)l, 16, 0, 0);
}
__device__ __forceinline__ f32x4 mfma16(bf16x8 a, bf16x8 b, f32x4 c) {
  return __builtin_amdgcn_mfma_f32_16x16x32_bf16(a, b, c, 0, 0, 0);
}
__device__ __forceinline__ float wave_sum(float v) {
#pragma unroll
  for (int st = 1; st < 64; st <<= 1) v += __shfl_xor(v, st);
  return v;
}

// ---------------- Threefry-2x32 (JAX-exact, 20 rounds) ----------------
__device__ __forceinline__ void tf2x32(unsigned k0, unsigned k1, unsigned x0,
                                       unsigned x1, unsigned& y0, unsigned& y1) {
  unsigned ks0 = k0, ks1 = k1, ks2 = k0 ^ k1 ^ 0x1BD11BDAu;
  x0 += ks0; x1 += ks1;
  const int rA[4] = {13, 15, 26, 6};
  const int rB[4] = {17, 29, 16, 24};
#define ROTL(v, d) (((v) << (d)) | ((v) >> (32 - (d))))
#define RG(R)                                     \
  _Pragma("unroll") for (int i = 0; i < 4; i++) { \
    x0 += x1; x1 = ROTL(x1, R[i]); x1 ^= x0;      \
  }
  RG(rA); x0 += ks1; x1 += ks2 + 1u;
  RG(rB); x0 += ks2; x1 += ks0 + 2u;
  RG(rA); x0 += ks0; x1 += ks1 + 3u;
  RG(rB); x0 += ks1; x1 += ks2 + 4u;
  RG(rA); x0 += ks2; x1 += ks0 + 5u;
#undef RG
#undef ROTL
  y0 = x0; y1 = x1;
}

// ---- 1. merged prep: W -> WhiT/WloT (transposed split); sup/qry -> bf16 ---
__global__ __launch_bounds__(256) void prep_k(
    const float* __restrict__ W, const float* __restrict__ sup,
    const float* __restrict__ qry, short* __restrict__ WhiT,
    short* __restrict__ WloT, short* __restrict__ Shi,
    short* __restrict__ Slo, short* __restrict__ Qhi) {
  __shared__ float tile[64][65];
  int t = threadIdx.x;
  if (blockIdx.x < 1024) {  // prepw: 64 k-tiles x 16 n-tiles of 64x64
    int bk = blockIdx.x & 63, bn = blockIdx.x >> 6;
#pragma unroll
    for (int i = 0; i < 4; i++) {
      int row = i * 16 + (t >> 4);
      int col = (t & 15) * 4;
      f32x4 v =
          *(const f32x4*)(W + (size_t)(bk * 64 + row) * 1024 + bn * 64 + col);
      tile[row][col + 0] = v[0]; tile[row][col + 1] = v[1];
      tile[row][col + 2] = v[2]; tile[row][col + 3] = v[3];
    }
    __syncthreads();
#pragma unroll
    for (int i = 0; i < 4; i++) {
      int nrow = i * 16 + (t >> 4);
      int kcol = (t & 15) * 4;
      s16x4 hv, lv;
#pragma unroll
      for (int e = 0; e < 4; e++) {
        float v = tile[kcol + e][nrow];
        unsigned short h = f2bf(v);
        hv[e] = (short)h;
        lv[e] = (short)f2bf(v - bf2f(h));
      }
      size_t off = (size_t)(bn * 64 + nrow) * 4096 + bk * 64 + kcol;
      *(s16x4*)(WhiT + off) = hv;
      *(s16x4*)(WloT + off) = lv;
    }
  } else {  // prepa
    size_t gid = (size_t)(blockIdx.x - 1024) * 256 + t;  // one 8-elem chunk
    const size_t sup_n8 = (size_t)4096 * 4096 / 8;
    if (gid < sup_n8) {
      const float* src = sup + gid * 8;
      f32x4 v0 = *(const f32x4*)src, v1 = *(const f32x4*)(src + 4);
      s16x8 h, l;
#pragma unroll
      for (int e = 0; e < 4; e++) {
        unsigned short hh = f2bf(v0[e]);
        h[e] = (short)hh; l[e] = (short)f2bf(v0[e] - bf2f(hh));
      }
#pragma unroll
      for (int e = 0; e < 4; e++) {
        unsigned short hh = f2bf(v1[e]);
        h[4 + e] = (short)hh; l[4 + e] = (short)f2bf(v1[e] - bf2f(hh));
      }
      *(s16x8*)(Shi + gid * 8) = h;
      *(s16x8*)(Slo + gid * 8) = l;
    } else {
      size_t q = gid - sup_n8;
      const float* src = qry + q * 8;
      f32x4 v0 = *(const f32x4*)src, v1 = *(const f32x4*)(src + 4);
      s16x8 h;
#pragma unroll
      for (int e = 0; e < 4; e++) h[e] = (short)f2bf(v0[e]);
#pragma unroll
      for (int e = 0; e < 4; e++) h[4 + e] = (short)f2bf(v1[e]);
      *(s16x8*)(Qhi + q * 8) = h;
    }
  }
}

// ---- 2a. support GEMM: BM=64, 3-product hi/lo, 48 KiB LDS (3 blk/CU) ------
__global__ __launch_bounds__(256) void gemm_sup_k(
    const short* __restrict__ Shi, const short* __restrict__ Slo,
    const short* __restrict__ WhiT, const short* __restrict__ WloT,
    const float* __restrict__ bias, float* __restrict__ emb) {
  __shared__ short lds[24576];  // 48 KiB
  short* Ah = lds;              // [64][64]
  short* Al = lds + 4096;       // [64][64]
  short* Bh = lds + 8192;       // [128][64]
  short* Bl = lds + 16384;      // [128][64]
  const int bid = blockIdx.x;
  const int bm = bid & 63, bn = bid >> 6;  // siblings differ by 64 -> same XCD
  const int t = threadIdx.x, lane = t & 63, w = t >> 6;
  const int wr = w >> 1, wc = w & 1;  // wave tile 32 x 64
  const int fr = lane & 15, kg = lane >> 4;
  const int ls = lane >> 3, lc = lane & 7;
  const short* Ag = Shi + (size_t)bm * 64 * 4096;
  const short* Alg = Slo + (size_t)bm * 64 * 4096;
  f32x4 acc[2][4] = {};

  for (int kt = 0; kt < 64; ++kt) {
    const int k0 = kt * 64;
    __syncthreads();
    const int cch = (lc ^ ls) * 8;
#pragma unroll
    for (int j = 0; j < 2; j++) {
      int rowl = w * 16 + j * 8 + ls;
      size_t aoff = (size_t)rowl * 4096 + k0 + cch;
      int ldst = (w * 16 + j * 8) * 64;
      gload_lds16(Ag + aoff, Ah + ldst);
      gload_lds16(Alg + aoff, Al + ldst);
    }
#pragma unroll
    for (int j = 0; j < 4; j++) {
      int rowl = w * 32 + j * 8 + ls;
      size_t boff = (size_t)(bn * 128 + rowl) * 4096 + k0 + cch;
      int ldst = (w * 32 + j * 8) * 64;
      gload_lds16(WhiT + boff, Bh + ldst);
      gload_lds16(WloT + boff, Bl + ldst);
    }
    __syncthreads();
#pragma unroll
    for (int ks = 0; ks < 2; ++ks) {
      const int cx = ((ks * 4 + kg) ^ (fr & 7)) * 8;
      bf16x8 ahf[2], alf[2], bhf[4], blf[4];
#pragma unroll
      for (int mi = 0; mi < 2; mi++) {
        int arow = wr * 32 + mi * 16 + fr;
        ahf[mi] = __builtin_bit_cast(bf16x8, *(const s16x8*)(Ah + arow * 64 + cx));
        alf[mi] = __builtin_bit_cast(bf16x8, *(const s16x8*)(Al + arow * 64 + cx));
      }
#pragma unroll
      for (int ni = 0; ni < 4; ni++) {
        int brow = wc * 64 + ni * 16 + fr;
        bhf[ni] = __builtin_bit_cast(bf16x8, *(const s16x8*)(Bh + brow * 64 + cx));
        blf[ni] = __builtin_bit_cast(bf16x8, *(const s16x8*)(Bl + brow * 64 + cx));
      }
#pragma unroll
      for (int mi = 0; mi < 2; mi++)
#pragma unroll
        for (int ni = 0; ni < 4; ni++) {
          acc[mi][ni] = mfma16(ahf[mi], bhf[ni], acc[mi][ni]);
          acc[mi][ni] = mfma16(ahf[mi], blf[ni], acc[mi][ni]);
          acc[mi][ni] = mfma16(alf[mi], bhf[ni], acc[mi][ni]);
        }
    }
  }
#pragma unroll
  for (int ni = 0; ni < 4; ni++) {
    int gc = bn * 128 + wc * 64 + ni * 16 + fr;
    float bv = bias[gc];
#pragma unroll
    for (int mi = 0; mi < 2; mi++) {
      int gr = bm * 64 + wr * 32 + mi * 16 + kg * 4;
#pragma unroll
      for (int r = 0; r < 4; r++)
        emb[(size_t)(gr + r) * 1024 + gc] = acc[mi][ni][r] + bv;
    }
  }
}

// ---- 2b. query GEMM: BM=128, 1-product, 32 KiB LDS (5 blk/CU) -------------
__global__ __launch_bounds__(256) void gemm_qry_k(
    const short* __restrict__ Qhi, const short* __restrict__ WhiT,
    const float* __restrict__ bias, float* __restrict__ emb) {
  __shared__ short lds[16384];  // 32 KiB: Ah[128][64], Bh[128][64]
  short* Ah = lds;
  short* Bh = lds + 8192;
  const int bid = blockIdx.x;
  const int bm = bid & 63, bn = bid >> 6;  // siblings differ by 64 -> same XCD
  const int t = threadIdx.x, lane = t & 63, w = t >> 6;
  const int wr = w >> 1, wc = w & 1;
  const int fr = lane & 15, kg = lane >> 4;
  const int ls = lane >> 3, lc = lane & 7;
  const short* Ag = Qhi + (size_t)bm * 128 * 4096;
  f32x4 acc[4][4] = {};

  for (int kt = 0; kt < 64; ++kt) {
    const int k0 = kt * 64;
    __syncthreads();
    const int cch = (lc ^ ls) * 8;
#pragma unroll
    for (int j = 0; j < 4; j++) {
      int rowl = w * 32 + j * 8 + ls;
      size_t aoff = (size_t)rowl * 4096 + k0 + cch;
      size_t boff = (size_t)(bn * 128 + rowl) * 4096 + k0 + cch;
      int ldst = (w * 32 + j * 8) * 64;
      gload_lds16(Ag + aoff, Ah + ldst);
      gload_lds16(WhiT + boff, Bh + ldst);
    }
    __syncthreads();
#pragma unroll
    for (int ks = 0; ks < 2; ++ks) {
      const int cx = ((ks * 4 + kg) ^ (fr & 7)) * 8;
      bf16x8 ahf[4], bhf[4];
#pragma unroll
      for (int mi = 0; mi < 4; mi++) {
        int arow = wr * 64 + mi * 16 + fr;
        ahf[mi] = __builtin_bit_cast(bf16x8, *(const s16x8*)(Ah + arow * 64 + cx));
      }
#pragma unroll
      for (int ni = 0; ni < 4; ni++) {
        int brow = wc * 64 + ni * 16 + fr;
        bhf[ni] = __builtin_bit_cast(bf16x8, *(const s16x8*)(Bh + brow * 64 + cx));
      }
#pragma unroll
      for (int mi = 0; mi < 4; mi++)
#pragma unroll
        for (int ni = 0; ni < 4; ni++)
          acc[mi][ni] = mfma16(ahf[mi], bhf[ni], acc[mi][ni]);
    }
  }
#pragma unroll
  for (int ni = 0; ni < 4; ni++) {
    int gc = bn * 128 + wc * 64 + ni * 16 + fr;
    float bv = bias[gc];
#pragma unroll
    for (int mi = 0; mi < 4; mi++) {
      int gr = 4096 + bm * 128 + wr * 64 + mi * 16 + kg * 4;
#pragma unroll
      for (int r = 0; r < 4; r++)
        emb[(size_t)(gr + r) * 1024 + gc] = acc[mi][ni][r] + bv;
    }
  }
}

// ---- 2'. fallback GEMM (in-loop convert; used when ws too small) ----------
__global__ __launch_bounds__(256) void gemm_all_k(
    const float* __restrict__ sup, const float* __restrict__ qry,
    const short* __restrict__ WhiT, const short* __restrict__ WloT,
    const float* __restrict__ bias, float* __restrict__ emb) {
  __shared__ short lds[4 * 128 * 64];
  short* Ah = lds;
  short* Al = lds + 8192;
  short* Bh = lds + 16384;
  short* Bl = lds + 24576;
  const int bid = blockIdx.x;
  const int bm = bid % 96, bn = bid / 96;
  const bool is_sup = bm < 32;
  const int t = threadIdx.x, lane = t & 63, w = t >> 6;
  const int wr = w >> 1, wc = w & 1;
  const int fr = lane & 15, kg = lane >> 4;
  const float* Abase = is_sup ? (sup + (size_t)bm * 128 * 4096)
                              : (qry + (size_t)(bm - 32) * 128 * 4096);
  f32x4 acc[4][4] = {};
  const int ls = lane >> 3, lc = lane & 7;

  for (int kt = 0; kt < 64; ++kt) {
    const int k0 = kt * 64;
    __syncthreads();
#pragma unroll
    for (int i = 0; i < 4; i++) {
      int row = i * 32 + w * 8 + ls;
      const float* src = Abase + (size_t)row * 4096 + k0 + lc * 8;
      f32x4 v0 = *(const f32x4*)src;
      f32x4 v1 = *(const f32x4*)(src + 4);
      s16x8 hs;
#pragma unroll
      for (int e = 0; e < 4; e++) hs[e] = (short)f2bf(v0[e]);
#pragma unroll
      for (int e = 0; e < 4; e++) hs[4 + e] = (short)f2bf(v1[e]);
      int chunk = lc ^ (row & 7);
      *(s16x8*)(Ah + row * 64 + chunk * 8) = hs;
      if (is_sup) {
        s16x8 lsv;
#pragma unroll
        for (int e = 0; e < 4; e++)
          lsv[e] = (short)f2bf(v0[e] - bf2f((unsigned short)hs[e]));
#pragma unroll
        for (int e = 0; e < 4; e++)
          lsv[4 + e] = (short)f2bf(v1[e] - bf2f((unsigned short)hs[4 + e]));
        *(s16x8*)(Al + row * 64 + chunk * 8) = lsv;
      }
    }
#pragma unroll
    for (int j = 0; j < 4; j++) {
      int rowl = w * 32 + j * 8 + ls;
      int cch = (lc ^ (ls & 7)) * 8;
      size_t goff = (size_t)(bn * 128 + rowl) * 4096 + k0 + cch;
      gload_lds16(WhiT + goff, Bh + (w * 32 + j * 8) * 64);
      if (is_sup) gload_lds16(WloT + goff, Bl + (w * 32 + j * 8) * 64);
    }
    __syncthreads();
#pragma unroll
    for (int ks = 0; ks < 2; ++ks) {
      const int cx = ((ks * 4 + kg) ^ (fr & 7)) * 8;
      bf16x8 ahf[4], bhf[4];
#pragma unroll
      for (int mi = 0; mi < 4; mi++) {
        int arow = wr * 64 + mi * 16 + fr;
        ahf[mi] = __builtin_bit_cast(bf16x8, *(const s16x8*)(Ah + arow * 64 + cx));
      }
#pragma unroll
      for (int ni = 0; ni < 4; ni++) {
        int brow = wc * 64 + ni * 16 + fr;
        bhf[ni] = __builtin_bit_cast(bf16x8, *(const s16x8*)(Bh + brow * 64 + cx));
      }
      if (is_sup) {
        bf16x8 alf[4], blf[4];
#pragma unroll
        for (int mi = 0; mi < 4; mi++) {
          int arow = wr * 64 + mi * 16 + fr;
          alf[mi] =
              __builtin_bit_cast(bf16x8, *(const s16x8*)(Al + arow * 64 + cx));
        }
#pragma unroll
        for (int ni = 0; ni < 4; ni++) {
          int brow = wc * 64 + ni * 16 + fr;
          blf[ni] =
              __builtin_bit_cast(bf16x8, *(const s16x8*)(Bl + brow * 64 + cx));
        }
#pragma unroll
        for (int mi = 0; mi < 4; mi++)
#pragma unroll
          for (int ni = 0; ni < 4; ni++) {
            acc[mi][ni] = mfma16(ahf[mi], bhf[ni], acc[mi][ni]);
            acc[mi][ni] = mfma16(ahf[mi], blf[ni], acc[mi][ni]);
            acc[mi][ni] = mfma16(alf[mi], bhf[ni], acc[mi][ni]);
          }
      } else {
#pragma unroll
        for (int mi = 0; mi < 4; mi++)
#pragma unroll
          for (int ni = 0; ni < 4; ni++)
            acc[mi][ni] = mfma16(ahf[mi], bhf[ni], acc[mi][ni]);
      }
    }
  }
#pragma unroll
  for (int ni = 0; ni < 4; ni++) {
    int gc = bn * 128 + wc * 64 + ni * 16 + fr;
    float bv = bias[gc];
#pragma unroll
    for (int mi = 0; mi < 4; mi++) {
      int gr = bm * 128 + wr * 64 + mi * 16 + kg * 4;
#pragma unroll
      for (int r = 0; r < 4; r++)
        emb[(size_t)(gr + r) * 1024 + gc] = acc[mi][ni][r] + bv;
    }
  }
}

// ---------------- 3. per-class Gram G = S S^T (fp32 vector) ----------------
__global__ __launch_bounds__(256) void gram_k(const float* __restrict__ emb,
                                              float* __restrict__ G) {
  int c = blockIdx.x >> 4, tl = blockIdx.x & 15, ti = tl >> 2, tj = tl & 3;
  __shared__ float As[64][36];
  __shared__ float Bs[32][68];
  int t = threadIdx.x, ty = t >> 4, tx = t & 15;
  const float* base = emb + (size_t)c * 256 * 1024;
  float acc[4][4] = {};
  for (int k0 = 0; k0 < 1024; k0 += 32) {
    __syncthreads();
    {
      int r = t >> 2, seg = t & 3;
      const float* pa = base + (size_t)(ti * 64 + r) * 1024 + k0 + seg * 8;
      f32x4 va0 = *(const f32x4*)pa, va1 = *(const f32x4*)(pa + 4);
      *(f32x4*)(&As[r][seg * 8]) = va0;
      *(f32x4*)(&As[r][seg * 8 + 4]) = va1;
      const float* pb = base + (size_t)(tj * 64 + r) * 1024 + k0 + seg * 8;
      f32x4 vb0 = *(const f32x4*)pb, vb1 = *(const f32x4*)(pb + 4);
#pragma unroll
      for (int e = 0; e < 4; e++) Bs[seg * 8 + e][r] = vb0[e];
#pragma unroll
      for (int e = 0; e < 4; e++) Bs[seg * 8 + 4 + e][r] = vb1[e];
    }
    __syncthreads();
#pragma unroll 4
    for (int kk = 0; kk < 32; kk++) {
      float a0 = As[ty * 4 + 0][kk], a1 = As[ty * 4 + 1][kk];
      float a2 = As[ty * 4 + 2][kk], a3 = As[ty * 4 + 3][kk];
      f32x4 bv = *(const f32x4*)(&Bs[kk][tx * 4]);
#pragma unroll
      for (int jdx = 0; jdx < 4; jdx++) {
        acc[0][jdx] = fmaf(a0, bv[jdx], acc[0][jdx]);
        acc[1][jdx] = fmaf(a1, bv[jdx], acc[1][jdx]);
        acc[2][jdx] = fmaf(a2, bv[jdx], acc[2][jdx]);
        acc[3][jdx] = fmaf(a3, bv[jdx], acc[3][jdx]);
      }
    }
  }
#pragma unroll
  for (int i = 0; i < 4; i++) {
    int gr = ti * 64 + ty * 4 + i;
#pragma unroll
    for (int j = 0; j < 4; j++)
      G[(size_t)c * 65536 + (size_t)gr * 256 + tj * 64 + tx * 4 + j] = acc[i][j];
  }
}

// ---------------- 3b. overwrite G diagonal with f64-exact |x_i|^2 ----------
__global__ __launch_bounds__(256) void diag_k(const float* __restrict__ emb,
                                              float* __restrict__ G) {
  int r = blockIdx.x * 4 + (threadIdx.x >> 6);  // support row 0..4095
  int lane = threadIdx.x & 63;
  const float* x = emb + (size_t)r * 1024;
  double acc = 0.0;
#pragma unroll
  for (int ch = 0; ch < 16; ch++) {
    float v = x[ch * 64 + lane];
    acc = fma((double)v, (double)v, acc);
  }
#pragma unroll
  for (int st = 1; st < 64; st <<= 1) acc += __shfl_xor(acc, st);
  if (lane == 0) {
    int c = r >> 8, i = r & 255;
    G[(size_t)c * 65536 + (size_t)i * 256 + i] = (float)acc;
  }
}

// -------- 4. per-class kmeans, incremental fp32 S updates (100 iters) ------
__global__ __launch_bounds__(256) void kmeans2_k(const float* __restrict__ G,
                                                 float* __restrict__ wts) {
  const int c = blockIdx.x;
  const int t = threadIdx.x, lane = t & 63, w = t >> 6;
  __shared__ unsigned dmL[256], nmL[256];
  __shared__ unsigned short chg[256];
  __shared__ unsigned sk[256];
  __shared__ unsigned idx5[5];
  __shared__ float Tpart[4][5], Tu[5], C2[5], Minv[5];
  __shared__ int Hp[4][5], Ncnt[5], cntW[4];

  // --- RNG (threefry PARTITIONABLE mode, JAX >= 0.4.36 default)
  {
    unsigned o0, o1, s0k, s1k, y0, y1;
    tf2x32(0u, 42u, 0u, (unsigned)c, o0, o1);
    tf2x32(o0, o1, 0u, 1u, s0k, s1k);
    tf2x32(s0k, s1k, 0u, (unsigned)t, y0, y1);
    sk[t] = y0 ^ y1;
  }
  __syncthreads();
  {
    unsigned kt_ = sk[t];
    int rank = 0;
    for (int j = 0; j < 256; j++) {
      unsigned kj = sk[j];
      rank += (kj < kt_ || (kj == kt_ && j < t)) ? 1 : 0;
    }
    if (rank < 5) idx5[rank] = (unsigned)t;  // stable sort -> first 5 of perm
  }
  if (t < 5) Minv[t] = 1.0f;
  __syncthreads();

  unsigned m = 0;
#pragma unroll
  for (int k = 0; k < 5; k++) m |= (idx5[k] == (unsigned)t) ? (1u << k) : 0u;

  const float* Gc = G + (size_t)c * 65536;
  float s0 = Gc[(size_t)idx5[0] * 256 + t];
  float s1 = Gc[(size_t)idx5[1] * 256 + t];
  float s2 = Gc[(size_t)idx5[2] * 256 + t];
  float s3 = Gc[(size_t)idx5[3] * 256 + t];
  float s4 = Gc[(size_t)idx5[4] * 256 + t];

  for (int it = 0; it < 100; ++it) {
    float v0 = (m & 1u) ? s0 : 0.0f;
    float v1 = (m & 2u) ? s1 : 0.0f;
    float v2 = (m & 4u) ? s2 : 0.0f;
    float v3 = (m & 8u) ? s3 : 0.0f;
    float v4 = (m & 16u) ? s4 : 0.0f;
#pragma unroll
    for (int st = 1; st < 64; st <<= 1) {
      v0 += __shfl_xor(v0, st); v1 += __shfl_xor(v1, st);
      v2 += __shfl_xor(v2, st); v3 += __shfl_xor(v3, st);
      v4 += __shfl_xor(v4, st);
    }
    if (lane == 0) {
      Tpart[w][0] = v0; Tpart[w][1] = v1; Tpart[w][2] = v2;
      Tpart[w][3] = v3; Tpart[w][4] = v4;
    }
    __syncthreads();
    if (t < 5) {
      float T = Tpart[0][t] + Tpart[1][t] + Tpart[2][t] + Tpart[3][t];
      float iv = Minv[t];
      Tu[t] = T * iv * iv;   // |c_k|^2
      C2[t] = -2.0f * iv;    // coefficient on S
    }
    __syncthreads();
    float d0 = fmaf(C2[0], s0, Tu[0]);
    float d1 = fmaf(C2[1], s1, Tu[1]);
    float d2 = fmaf(C2[2], s2, Tu[2]);
    float d3 = fmaf(C2[3], s3, Tu[3]);
    float d4 = fmaf(C2[4], s4, Tu[4]);
    int a_t = 0;
    float dmn = d0;
    if (d1 < dmn) { dmn = d1; a_t = 1; }
    if (d2 < dmn) { dmn = d2; a_t = 2; }
    if (d3 < dmn) { dmn = d3; a_t = 3; }
    if (d4 < dmn) { dmn = d4; a_t = 4; }
#pragma unroll
    for (int k = 0; k < 5; k++) {
      unsigned long long bal = __ballot(a_t == k);
      if (lane == 0) Hp[w][k] = (int)__popcll(bal);
    }
    __syncthreads();
    if (t < 5) Ncnt[t] = Hp[0][t] + Hp[1][t] + Hp[2][t] + Hp[3][t];
    __syncthreads();
    unsigned nm = 0;
#pragma unroll
    for (int k = 0; k < 5; k++) {
      int bit = (Ncnt[k] > 0) ? (a_t == k ? 1 : 0) : (int)((m >> k) & 1u);
      nm |= ((unsigned)bit) << k;
    }
    unsigned dmb = nm ^ m;
    unsigned long long bal = __ballot(dmb != 0);
    int myrank = (int)__popcll(bal & ((1ull << lane) - 1ull));
    if (lane == 0) cntW[w] = (int)__popcll(bal);
    nmL[t] = nm; dmL[t] = dmb;
    __syncthreads();
    int base = 0, ntot = 0;
#pragma unroll
    for (int ww = 0; ww < 4; ww++) {
      int cw = cntW[ww];
      if (ww < w) base += cw;
      ntot += cw;
    }
    if (ntot == 0) break;  // fixed point: remaining iterations are no-ops
    if (dmb != 0) chg[base + myrank] = (unsigned short)t;
    m = nm;
    if (t < 5 && Ncnt[t] > 0) Minv[t] = 1.0f / (float)Ncnt[t];
    __syncthreads();
    for (int p = 0; p < ntot; p += 4) {
      float g[4]; int jj[4];
#pragma unroll
      for (int q = 0; q < 4; q++) {
        int idx = p + q;
        jj[q] = (idx < ntot) ? (int)chg[idx] : -1;
        g[q] = (jj[q] >= 0) ? Gc[(size_t)jj[q] * 256 + t] : 0.0f;
      }
#pragma unroll
      for (int q = 0; q < 4; q++) {
        if (jj[q] < 0) continue;
        unsigned db = dmL[jj[q]], nb = nmL[jj[q]];
        float gv = g[q];
        if (db & 1u)  s0 += (nb & 1u)  ? gv : -gv;
        if (db & 2u)  s1 += (nb & 2u)  ? gv : -gv;
        if (db & 4u)  s2 += (nb & 4u)  ? gv : -gv;
        if (db & 8u)  s3 += (nb & 8u)  ? gv : -gv;
        if (db & 16u) s4 += (nb & 16u) ? gv : -gv;
      }
    }
    __syncthreads();
  }
  float wv = 0.0f;
#pragma unroll
  for (int k = 0; k < 5; k++)
    if ((m >> k) & 1u) wv += 0.2f * Minv[k];
  wts[c * 256 + t] = wv;
}

// ---- 6a. proto partials: 256 blocks (c, 16-row segment) -------------------
__global__ __launch_bounds__(256) void proto1_k(const float* __restrict__ emb,
                                                const float* __restrict__ wts,
                                                float* __restrict__ part) {
  int c = blockIdx.x & 15, seg = blockIdx.x >> 4, t = threadIdx.x;
  __shared__ float wl[16];
  if (t < 16) wl[t] = wts[c * 256 + seg * 16 + t];
  __syncthreads();
  f32x4 acc = {};
  const float* base = emb + (size_t)(c * 256 + seg * 16) * 1024 + t * 4;
#pragma unroll
  for (int j = 0; j < 16; j++) {
    f32x4 v = *(const f32x4*)(base + (size_t)j * 1024);
    float wj = wl[j];
#pragma unroll
    for (int e = 0; e < 4; e++) acc[e] = fmaf(wj, v[e], acc[e]);
  }
  *(f32x4*)(part + ((size_t)seg * 16 + c) * 1024 + t * 4) = acc;
}

// ---- 6b. proto reduce: fixed ascending-seg order (deterministic) ----------
__global__ __launch_bounds__(256) void proto2_k(const float* __restrict__ part,
                                                float* __restrict__ protos) {
  int c = blockIdx.x, t = threadIdx.x;
  f32x4 acc = {};
#pragma unroll
  for (int seg = 0; seg < 16; seg++) {
    f32x4 v = *(const f32x4*)(part + ((size_t)seg * 16 + c) * 1024 + t * 4);
#pragma unroll
    for (int e = 0; e < 4; e++) acc[e] += v[e];
  }
  *(f32x4*)(protos + (size_t)c * 1024 + t * 4) = acc;
}

// ---- 6'. fallback single-kernel proto ------------------------------------
__global__ __launch_bounds__(256) void proto_k(const float* __restrict__ emb,
                                               const float* __restrict__ wts,
                                               float* __restrict__ protos) {
  int c = blockIdx.x, t = threadIdx.x;
  __shared__ float wl[256];
  wl[t] = wts[c * 256 + t];
  __syncthreads();
  f32x4 acc = {};
  const float* base = emb + (size_t)c * 256 * 1024 + t * 4;
  for (int j = 0; j < 256; j++) {
    f32x4 v = *(const f32x4*)(base + (size_t)j * 1024);
    float wj = wl[j];
#pragma unroll
    for (int e = 0; e < 4; e++) acc[e] = fmaf(wj, v[e], acc[e]);
  }
  *(f32x4*)(protos + (size_t)c * 1024 + t * 4) = acc;
}

// ---------------- 7. output: -cdist(query_emb, protos) ---------------------
__global__ __launch_bounds__(256) void dist_k(const float* __restrict__ emb,
                                              const float* __restrict__ protos,
                                              float* __restrict__ out) {
  __shared__ float P[16 * 1024];  // 64 KiB
  int t = threadIdx.x, lane = t & 63, w = t >> 6;
#pragma unroll
  for (int i = 0; i < 16; i++) {
    int off = i * 1024 + t * 4;
    *(f32x4*)(P + off) = *(const f32x4*)(protos + off);
  }
  __syncthreads();
  float psq_keep = 0.0f;
  for (int p = 0; p < 16; p++) {
    float partial = 0.0f;
#pragma unroll
    for (int ch = 0; ch < 16; ch++) {
      float x = P[p * 1024 + ch * 64 + lane];
      partial = fmaf(x, x, partial);
    }
    partial = wave_sum(partial);
    if (lane == p) psq_keep = partial;
  }
  const float* qbase = emb + (size_t)4096 * 1024;
  int r0 = blockIdx.x * 16 + w * 4;
  for (int ri = 0; ri < 4; ri++) {
    int row = r0 + ri;
    const float* q = qbase + (size_t)row * 1024;
    float qv[16];
#pragma unroll
    for (int ch = 0; ch < 16; ch++) qv[ch] = q[ch * 64 + lane];
    float qsq = 0.0f;
#pragma unroll
    for (int ch = 0; ch < 16; ch++) qsq = fmaf(qv[ch], qv[ch], qsq);
    qsq = wave_sum(qsq);
    float dsel = 0.0f;
    for (int p = 0; p < 16; p++) {
      float dp = 0.0f;
#pragma unroll
      for (int ch = 0; ch < 16; ch++)
        dp = fmaf(qv[ch], P[p * 1024 + ch * 64 + lane], dp);
      dp = wave_sum(dp);
      if (lane == p) dsel = dp;
    }
    if (lane < 16) {
      float d2 = qsq - 2.0f * dsel + psq_keep;
      d2 = fmaxf(d2, 0.0f);
      out[(size_t)row * 16 + lane] = -sqrtf(d2);
    }
  }
}

// ---------------- launch ---------------------------------------------------
extern "C" void kernel_launch(void* const* d_in, const int* in_sizes, int n_in,
                              void* d_out, int out_size, void* d_ws,
                              size_t ws_size, hipStream_t stream) {
  const float* sup = (const float*)d_in[0];
  const float* qry = (const float*)d_in[1];
  const float* W = (const float*)d_in[2];
  const float* b = (const float*)d_in[3];
  float* out = (float*)d_out;
  char* ws = (char*)d_ws;
  (void)in_sizes; (void)n_in; (void)out_size;

  const size_t NEED_FAST = 206651392ULL;  // ~197 MiB
  if (ws_size >= NEED_FAST) {
    short* WhiT = (short*)(ws + 0);            //  8 MiB
    short* WloT = (short*)(ws + 8388608);      //  8 MiB
    short* Shi = (short*)(ws + 16777216);      // 32 MiB
    short* Slo = (short*)(ws + 50331648);      // 32 MiB
    short* Qhi = (short*)(ws + 83886080);      // 64 MiB
    float* emb = (float*)(ws + 150994944);     // 48 MiB
    float* G = (float*)(ws + 201326592);       //  4 MiB
    float* wts = (float*)(ws + 205520896);     // 16 KiB
    float* protos = (float*)(ws + 205537280);  // 64 KiB
    float* part = (float*)(ws + 205602816);    //  1 MiB

    prep_k<<<25600, 256, 0, stream>>>(W, sup, qry, WhiT, WloT, Shi, Slo, Qhi);
    gemm_sup_k<<<512, 256, 0, stream>>>(Shi, Slo, WhiT, WloT, b, emb);
    gemm_qry_k<<<512, 256, 0, stream>>>(Qhi, WhiT, b, emb);
    gram_k<<<256, 256, 0, stream>>>(emb, G);
    diag_k<<<1024, 256, 0, stream>>>(emb, G);
    kmeans2_k<<<16, 256, 0, stream>>>(G, wts);
    proto1_k<<<256, 256, 0, stream>>>(emb, wts, part);
    proto2_k<<<16, 256, 0, stream>>>(part, protos);
    dist_k<<<512, 256, 0, stream>>>(emb, protos, out);
  } else {
    short* WhiT = (short*)(ws + 0);
    short* WloT = (short*)(ws + 8388608);
    float* emb = (float*)(ws + 16777216);
    float* G = (float*)(ws + 67108864);
    float* wts = (float*)(ws + 71303168);
    float* protos = (float*)(ws + 71319552);

    prep_k<<<1024, 256, 0, stream>>>(W, sup, qry, WhiT, WloT, (short*)0,
                                     (short*)0, (short*)0);
    gemm_all_k<<<768, 256, 0, stream>>>(sup, qry, WhiT, WloT, b, emb);
    gram_k<<<256, 256, 0, stream>>>(emb, G);
    diag_k<<<1024, 256, 0, stream>>>(emb, G);
    kmeans2_k<<<16, 256, 0, stream>>>(G, wts);
    proto_k<<<16, 256, 0, stream>>>(emb, wts, protos);
    dist_k<<<512, 256, 0, stream>>>(emb, protos, out);
  }
}